// Round 5
// baseline (239.233 us; speedup 1.0000x reference)
//
// InputLayer Rayleigh-Sommerfeld — round 5: PLANAR complex output (re-plane, im-plane)
#include <hip/hip_runtime.h>

namespace rs5 {

constexpr int kN  = 96;
constexpr int kN2 = kN * kN;          // 9216
constexpr int kWaves = 4;
constexpr int kBlock = 64 * kWaves;   // 256
constexpr int kIters = kN2 / 64;      // 144

__global__ __launch_bounds__(kBlock) void rs_planar_v5(const float* __restrict__ img,
                                                       float* __restrict__ out) {
    const float dl      = (float)(1e-3 / 96.0);
    const float dz      = 0.01f;
    const float dz2     = dz * dz;
    const float lam_amp = (float)(1.0 / 1.55e-6);   // |1/(j*lambda)|
    const float inv_2pi = 1.0f / 6.2831855f;
    const float k32     = 6.2831855f / 1.55e-6f;    // fp32(2pi)/fp32(lambda)

    const int tid  = (int)threadIdx.x;
    const int lane = tid & 63;
    const int wid  = tid >> 6;

    // block-wide max over img (uniform[0,1): 0 is a safe identity)
    float vmax = 0.0f;
    for (int t = tid; t < kN2; t += kBlock) vmax = fmaxf(vmax, img[t]);
    for (int off = 32; off >= 1; off >>= 1) vmax = fmaxf(vmax, __shfl_xor(vmax, off, 64));
    __shared__ float smax[kWaves];
    if (lane == 0) smax[wid] = vmax;
    __syncthreads();
    float gmax = smax[0];
    for (int w = 1; w < kWaves; ++w) gmax = fmaxf(gmax, smax[w]);
    const float inv_max = 1.0f / gmax;

    // one wave per detector; det = di*96 + dj, x-coordinate follows FIRST index
    const int det = (int)blockIdx.x * kWaves + wid;
    const int di  = det / kN;
    const int dj  = det - di * kN;
    const float px = ((float)di + 0.5f) * dl;
    const float py = ((float)dj + 0.5f) * dl;

    float sum_re = 0.0f, sum_im = 0.0f;

    for (int it = 0; it < kIters; ++it) {
        const int src = it * 64 + lane;
        const int si  = src / kN;
        const int sj  = src - si * kN;

        const float ex = px - ((float)si + 0.5f) * dl;
        const float ey = py - ((float)sj + 0.5f) * dl;
        const float r  = sqrtf(ex * ex + ey * ey + dz2);

        const float theta = k32 * r;        // fp32 rounded phase, as the reference
        const float sn = sinf(theta);       // accurate libm, full reduction
        const float cs = cosf(theta);

        const float rinv = 1.0f / r;
        const float ampf = dz * rinv * rinv;          // dz / r^2
        const float near = rinv * inv_2pi;            // 1/(2*pi*r)
        const float wgt  = img[src] * inv_max * ampf; // (x/max)*dz/r^2

        sum_re += wgt * (near * cs + lam_amp * sn);   // Re[(near - j*L) e^{j theta}]
        sum_im += wgt * (near * sn - lam_amp * cs);   // Im[...]
    }

    for (int off = 32; off >= 1; off >>= 1) {
        sum_re += __shfl_xor(sum_re, off, 64);
        sum_im += __shfl_xor(sum_im, off, 64);
    }
    if (lane == 0) {
        out[det]       = sum_re;   // PLANAR: real plane first ...
        out[kN2 + det] = sum_im;   // ... then imag plane
    }
}

}  // namespace rs5

extern "C" void kernel_launch(void* const* d_in, const int* in_sizes, int n_in,
                              void* d_out, int out_size, void* d_ws, size_t ws_size,
                              hipStream_t stream) {
    (void)in_sizes; (void)n_in; (void)out_size; (void)d_ws; (void)ws_size;
    const float* img = (const float*)d_in[0];
    float* out = (float*)d_out;
    hipLaunchKernelGGL(rs5::rs_planar_v5, dim3(rs5::kN2 / rs5::kWaves), dim3(rs5::kBlock),
                       0, stream, img, out);
}

// Round 6
// 127.918 us; speedup vs baseline: 1.8702x; 1.8702x over previous
//
// InputLayer Rayleigh-Sommerfeld — round 6: HW transcendentals (v_sin/v_cos/v_rsq), planar output
#include <hip/hip_runtime.h>

#ifndef __has_builtin
#define __has_builtin(x) 0
#endif

namespace rs6 {

constexpr int kN  = 96;
constexpr int kN2 = kN * kN;          // 9216
constexpr int kWaves = 4;
constexpr int kBlock = 64 * kWaves;   // 256
constexpr int kIters = kN2 / 64;      // 144

__device__ __forceinline__ float sin_rev(float x) {
#if __has_builtin(__builtin_amdgcn_sinf)
    return __builtin_amdgcn_sinf(x);  // v_sin_f32: sin(2*pi*x), input in revolutions
#else
    return sinf(6.28318530717958647692f * x);
#endif
}
__device__ __forceinline__ float cos_rev(float x) {
#if __has_builtin(__builtin_amdgcn_cosf)
    return __builtin_amdgcn_cosf(x);  // v_cos_f32: cos(2*pi*x)
#else
    return cosf(6.28318530717958647692f * x);
#endif
}
__device__ __forceinline__ float rsq(float x) {
#if __has_builtin(__builtin_amdgcn_rsqf)
    return __builtin_amdgcn_rsqf(x);  // v_rsq_f32
#else
    return rsqrtf(x);
#endif
}

__global__ __launch_bounds__(kBlock) void rs_hwtrans_v6(const float* __restrict__ img,
                                                        float* __restrict__ out) {
    const float dl      = (float)(1e-3 / 96.0);
    const float dz      = 0.01f;
    const float dz2     = dz * dz;
    const float lam_amp = (float)(1.0 / 1.55e-6);   // |1/(j*lambda)|
    const float inv_2pi = 0.15915494309189535f;     // fp32(1/(2*pi))
    const float k32     = 6.2831855f / 1.55e-6f;    // fp32(2pi)/fp32(lambda) — ref's phase constant

    const int tid  = (int)threadIdx.x;
    const int lane = tid & 63;
    const int wid  = tid >> 6;

    // ---- block-wide max over img (uniform[0,1): 0 is a safe identity) ----
    float vmax = 0.0f;
    for (int t = tid; t < kN2; t += kBlock) vmax = fmaxf(vmax, img[t]);
    for (int off = 32; off >= 1; off >>= 1) vmax = fmaxf(vmax, __shfl_xor(vmax, off, 64));
    __shared__ float smax[kWaves];
    if (lane == 0) smax[wid] = vmax;
    __syncthreads();
    float gmax = smax[0];
    for (int w = 1; w < kWaves; ++w) gmax = fmaxf(gmax, smax[w]);
    const float inv_max = 1.0f / gmax;

    // ---- one wave per detector; det = di*96 + dj (x follows FIRST index) ----
    const int det = (int)blockIdx.x * kWaves + wid;
    const int di  = det / kN;
    const int dj  = det - di * kN;
    const float px = ((float)di + 0.5f) * dl;
    const float py = ((float)dj + 0.5f) * dl;

    float sum_re = 0.0f, sum_im = 0.0f;

    // per-lane incremental base-96 index: s = it*64 + lane, si = s/96, sj = s%96
    int sj = lane;   // lane < 64 < 96  =>  si = 0
    int si = 0;
    for (int it = 0; it < kIters; ++it) {
        const float xs = img[it * 64 + lane];
        const float ex = px - ((float)si + 0.5f) * dl;
        const float ey = py - ((float)sj + 0.5f) * dl;
        const float rr = fmaf(ex, ex, fmaf(ey, ey, dz2));

        const float rinv = rsq(rr);           // 1/r (~1-2 ulp)
        const float r    = rr * rinv;         // r = rr/sqrt(rr)

        // phase: theta quantized to fp32 exactly as the reference, then exact
        // fma-split reduction to revolutions for the HW sin/cos
        const float theta = k32 * r;
        const float hi = theta * inv_2pi;
        const float lo = fmaf(theta, inv_2pi, -hi);
        const float fr = (hi - floorf(hi)) + lo;
        const float sn = sin_rev(fr);
        const float cs = cos_rev(fr);

        const float ampf = (dz * rinv) * rinv;        // dz / r^2
        const float near = rinv * inv_2pi;            // 1/(2*pi*r)
        const float g    = xs * ampf;                 // x * dz/r^2  (1/max folded at end)

        sum_re = fmaf(g, fmaf(near, cs,  lam_amp * sn), sum_re);
        sum_im = fmaf(g, fmaf(near, sn, -(lam_amp * cs)), sum_im);

        // s += 64 in base 96 (at most one wrap since 64 < 96)
        sj += 64;
        if (sj >= kN) { sj -= kN; si += 1; }
    }

    for (int off = 32; off >= 1; off >>= 1) {
        sum_re += __shfl_xor(sum_re, off, 64);
        sum_im += __shfl_xor(sum_im, off, 64);
    }
    if (lane == 0) {
        out[det]       = sum_re * inv_max;   // PLANAR: real plane ...
        out[kN2 + det] = sum_im * inv_max;   // ... then imag plane
    }
}

}  // namespace rs6

extern "C" void kernel_launch(void* const* d_in, const int* in_sizes, int n_in,
                              void* d_out, int out_size, void* d_ws, size_t ws_size,
                              hipStream_t stream) {
    (void)in_sizes; (void)n_in; (void)out_size; (void)d_ws; (void)ws_size;
    const float* img = (const float*)d_in[0];
    float* out = (float*)d_out;
    hipLaunchKernelGGL(rs6::rs_hwtrans_v6, dim3(rs6::kN2 / rs6::kWaves), dim3(rs6::kBlock),
                       0, stream, img, out);
}

// Round 7
// 76.643 us; speedup vs baseline: 3.1214x; 1.6690x over previous
//
// InputLayer Rayleigh-Sommerfeld — round 7: shift-invariant LDS table + FMA-only main loop
#include <hip/hip_runtime.h>

namespace rs7 {

constexpr int kN   = 96;
constexpr int kN2  = kN * kN;        // 9216 sources / detectors
constexpr int kDetPerBlock = 256;    // 4 waves x 64 detectors
constexpr int kSiPerBlock  = 6;      // source rows per block
constexpr int kDetBlocks   = kN2 / kDetPerBlock;   // 36
constexpr int kSiSplits    = kN / kSiPerBlock;     // 16
constexpr int kGrid  = kDetBlocks * kSiSplits;     // 576
constexpr int kBlock = 256;
constexpr int kMaxRows = 9;          // max distinct |di-si| rows per block
constexpr int kCols    = 2 * kN - 1; // 191 signed dj-sj offsets

__global__ __launch_bounds__(kBlock) void rs_table_v7(const float* __restrict__ img,
                                                      float* __restrict__ out) {
    const float dl      = (float)(1e-3 / 96.0);
    const float dz      = 0.01f;
    const float dz2     = dz * dz;
    const float lam_amp = (float)(1.0 / 1.55e-6);
    const float inv_2pi = 1.0f / 6.2831855f;
    const float k32     = 6.2831855f / 1.55e-6f;   // fp32(2pi)/fp32(lambda)

    __shared__ float2 tab[kMaxRows * kCols];       // W[a - amin][djmsj + 95]
    __shared__ float  wts[kSiPerBlock * kN];       // raw img rows (1/max folded later)
    __shared__ float  smax[4];

    const int tid  = (int)threadIdx.x;
    const int lane = tid & 63;
    const int wid  = tid >> 6;

    const int db = (int)blockIdx.x >> 4;           // detector tile
    const int ss = (int)blockIdx.x & 15;           // source split
    const int d0 = db * kDetPerBlock;
    const int di_lo = d0 / kN;
    const int di_hi = (d0 + kDetPerBlock - 1) / kN;
    const int si_lo = ss * kSiPerBlock;
    const int si_hi = si_lo + kSiPerBlock - 1;

    // |di-si| row range for this block (wave-uniform scalars)
    int amin;
    if (di_lo <= si_hi && si_lo <= di_hi) amin = 0;
    else amin = (di_lo > si_hi) ? (di_lo - si_hi) : (si_lo - di_hi);
    const int amax  = max(di_hi - si_lo, si_hi - di_lo);
    const int nrows = amax - amin + 1;             // <= 9

    // ---- build table slice with accurate libm (<= 1719 entries) ----
    for (int e = tid; e < nrows * kCols; e += kBlock) {
        const int ra = e / kCols;
        const int c  = e - ra * kCols;
        const float ax = (float)(amin + ra) * dl;  // |di-si| * dl
        const float by = (float)(c - (kN - 1)) * dl;
        const float r  = sqrtf(ax * ax + by * by + dz2);
        const float theta = k32 * r;               // fp32-rounded phase, as reference
        float sn, cs;
        __sincosf(theta, &sn, &cs);                // overwritten below; keeps vars init'd
        sn = sinf(theta);
        cs = cosf(theta);
        const float rinv = 1.0f / r;
        const float ampf = dz * rinv * rinv;
        const float near = rinv * inv_2pi;
        float2 wv;
        wv.x = ampf * (near * cs + lam_amp * sn);
        wv.y = ampf * (near * sn - lam_amp * cs);
        tab[e] = wv;
    }

    // ---- stage this block's weight rows (contiguous img range) ----
    for (int t = tid; t < kSiPerBlock * kN; t += kBlock) {
        wts[t] = img[si_lo * kN + t];
    }

    // ---- global max of img (uniform[0,1): 0 is safe identity) ----
    float vmax = 0.0f;
    for (int t = tid; t < kN2; t += kBlock) vmax = fmaxf(vmax, img[t]);
    for (int off = 32; off >= 1; off >>= 1) vmax = fmaxf(vmax, __shfl_xor(vmax, off, 64));
    if (lane == 0) smax[wid] = vmax;
    __syncthreads();
    const float inv_max = 1.0f / fmaxf(fmaxf(smax[0], smax[1]), fmaxf(smax[2], smax[3]));

    // ---- main loop: 2 LDS reads + 2 FMA per 64 pairs ----
    const int det = d0 + wid * 64 + lane;
    const int di  = det / kN;
    const int dj  = det - di * kN;

    float acc_re = 0.0f, acc_im = 0.0f;

    for (int sl = 0; sl < kSiPerBlock; ++sl) {
        const int si = si_lo + sl;
        int av = di - si;
        if (av < 0) av = -av;
        const float2* __restrict__ rowp = tab + (av - amin) * kCols + dj;  // + (95 - sj) below
        const float*  __restrict__ wrow = wts + sl * kN;
#pragma unroll
        for (int sj = 0; sj < kN; ++sj) {
            const float2 wv  = rowp[(kN - 1) - sj];   // W[a][dj - sj + 95]
            const float  wgt = wrow[sj];              // broadcast
            acc_re = fmaf(wv.x, wgt, acc_re);
            acc_im = fmaf(wv.y, wgt, acc_im);
        }
    }

    atomicAdd(&out[det],       acc_re * inv_max);   // planar: re plane
    atomicAdd(&out[kN2 + det], acc_im * inv_max);   // im plane
}

}  // namespace rs7

extern "C" void kernel_launch(void* const* d_in, const int* in_sizes, int n_in,
                              void* d_out, int out_size, void* d_ws, size_t ws_size,
                              hipStream_t stream) {
    (void)in_sizes; (void)n_in; (void)d_ws; (void)ws_size;
    const float* img = (const float*)d_in[0];
    float* out = (float*)d_out;
    hipMemsetAsync(d_out, 0, (size_t)out_size * sizeof(float), stream);
    hipLaunchKernelGGL(rs7::rs_table_v7, dim3(rs7::kGrid), dim3(rs7::kBlock),
                       0, stream, img, out);
}

// Round 8
// 70.705 us; speedup vs baseline: 3.3835x; 1.0840x over previous
//
// InputLayer Rayleigh-Sommerfeld — round 8: fp16-packed table, ds_read2 taps,
// scalar weight loads, slab accumulation + reduce kernel (no atomics, no memset)
#include <hip/hip_runtime.h>

namespace rs8 {

constexpr int kN    = 96;
constexpr int kN2   = kN * kN;          // 9216
constexpr int kOut2 = 2 * kN2;          // 18432 floats (planar re/im)
constexpr int kDetPerBlock = 256;
constexpr int kDetBlocks   = kN2 / kDetPerBlock;  // 36
constexpr int kSiPerBlock  = 4;
constexpr int kSplits      = kN / kSiPerBlock;    // 24
constexpr int kGrid  = kDetBlocks * kSplits;      // 864
constexpr int kBlock = 256;
constexpr int kCols  = 2 * kN - 1;      // 191
constexpr int kMaxRows = 8;             // |di-si| row span per block <= 7
constexpr float kScale    = 1.0f / 65536.0f;   // fp16 range scaling for W
constexpr float kUnscale  = 65536.0f;

typedef _Float16 half2_t __attribute__((ext_vector_type(2)));

__global__ __launch_bounds__(kBlock) void rs_conv_v8(const float* __restrict__ img,
                                                     float* __restrict__ ws) {
    const float dl      = (float)(1e-3 / 96.0);
    const float dz      = 0.01f;
    const float dz2     = dz * dz;
    const float lam_amp = (float)(1.0 / 1.55e-6);
    const float inv_2pi = 1.0f / 6.2831855f;
    const float k32     = 6.2831855f / 1.55e-6f;   // fp32(2pi)/fp32(lambda)

    __shared__ half2_t tab[kMaxRows * kCols];

    const int tid = (int)threadIdx.x;
    const int db  = (int)blockIdx.x / kSplits;     // detector tile
    const int ss  = (int)blockIdx.x % kSplits;     // source split
    const int d0  = db * kDetPerBlock;
    const int di_lo = d0 / kN;
    const int di_hi = (d0 + kDetPerBlock - 1) / kN;
    const int si_lo = ss * kSiPerBlock;
    const int si_hi = si_lo + kSiPerBlock - 1;

    int amin;
    if (di_lo <= si_hi && si_lo <= di_hi) amin = 0;
    else amin = (di_lo > si_hi) ? (di_lo - si_hi) : (si_lo - di_hi);
    const int amax  = max(di_hi - si_lo, si_hi - di_lo);
    const int nrows = amax - amin + 1;             // <= 8

    // ---- build fp16-packed table slice with accurate libm ----
    for (int e = tid; e < nrows * kCols; e += kBlock) {
        const int ra = e / kCols;
        const int c  = e - ra * kCols;
        const float ax = (float)(amin + ra) * dl;
        const float by = (float)(c - (kN - 1)) * dl;
        const float r  = sqrtf(ax * ax + by * by + dz2);
        const float theta = k32 * r;
        const float sn = sinf(theta);
        const float cs = cosf(theta);
        const float rinv = 1.0f / r;
        const float ampf = dz * rinv * rinv;
        const float near = rinv * inv_2pi;
        const float wre = ampf * (near * cs + lam_amp * sn);
        const float wim = ampf * (near * sn - lam_amp * cs);
        half2_t h;
        h.x = (_Float16)(wre * kScale);
        h.y = (_Float16)(wim * kScale);
        tab[e] = h;
    }
    __syncthreads();

    // ---- one thread per detector ----
    const int det = d0 + tid;
    const int di  = det / kN;
    const int dj  = det - di * kN;

    float acc_re = 0.0f, acc_im = 0.0f;

#pragma unroll
    for (int sl = 0; sl < kSiPerBlock; ++sl) {
        const int si = si_lo + sl;
        int av = di - si;
        if (av < 0) av = -av;
        const half2_t* __restrict__ rp = tab + (av - amin) * kCols + dj;
        const float2*  __restrict__ xw = (const float2*)(img + si * kN);  // uniform addr
#pragma unroll
        for (int t = 0; t < kN / 2; ++t) {
            const float2  x2 = xw[t];               // weights (x[si][2t], x[si][2t+1])
            const half2_t wa = rp[(kN - 1) - 2 * t];  // tap sj = 2t
            const half2_t wb = rp[(kN - 2) - 2 * t];  // tap sj = 2t+1 (adjacent dword)
            acc_re = fmaf((float)wa.x, x2.x, acc_re);
            acc_im = fmaf((float)wa.y, x2.x, acc_im);
            acc_re = fmaf((float)wb.x, x2.y, acc_re);
            acc_im = fmaf((float)wb.y, x2.y, acc_im);
        }
    }

    // private slab per split — no atomics, no zero-init needed
    float* slab = ws + (size_t)ss * kOut2;
    slab[det]       = acc_re;
    slab[kN2 + det] = acc_im;
}

__global__ __launch_bounds__(kBlock) void rs_reduce_v8(const float* __restrict__ img,
                                                       const float* __restrict__ ws,
                                                       float* __restrict__ out) {
    const int tid = (int)threadIdx.x;
    const int g   = (int)blockIdx.x * kBlock + tid;   // 0..18431

    // block-wide max over img (uniform[0,1): 0 is a safe identity)
    float vmax = 0.0f;
    for (int t = tid; t < kN2; t += kBlock) vmax = fmaxf(vmax, img[t]);
    for (int off = 32; off >= 1; off >>= 1) vmax = fmaxf(vmax, __shfl_xor(vmax, off, 64));
    __shared__ float smax[4];
    if ((tid & 63) == 0) smax[tid >> 6] = vmax;
    __syncthreads();
    const float gmax  = fmaxf(fmaxf(smax[0], smax[1]), fmaxf(smax[2], smax[3]));
    const float scale = kUnscale / gmax;              // undo fp16 scaling + 1/max

    float sum = 0.0f;
#pragma unroll
    for (int s = 0; s < kSplits; ++s) sum += ws[(size_t)s * kOut2 + g];
    out[g] = sum * scale;
}

}  // namespace rs8

extern "C" void kernel_launch(void* const* d_in, const int* in_sizes, int n_in,
                              void* d_out, int out_size, void* d_ws, size_t ws_size,
                              hipStream_t stream) {
    (void)in_sizes; (void)n_in; (void)out_size; (void)ws_size;
    const float* img = (const float*)d_in[0];
    float* ws  = (float*)d_ws;
    float* out = (float*)d_out;
    hipLaunchKernelGGL(rs8::rs_conv_v8, dim3(rs8::kGrid), dim3(rs8::kBlock), 0, stream,
                       img, ws);
    hipLaunchKernelGGL(rs8::rs_reduce_v8, dim3(rs8::kOut2 / rs8::kBlock), dim3(rs8::kBlock),
                       0, stream, img, ws, out);
}